// Round 1
// baseline (4898.658 us; speedup 1.0000x reference)
//
#include <hip/hip_runtime.h>
#include <cstddef>

#define LN_EPS 1e-5f
constexpr int NB = 16;   // rows per GEMM block

// ---------------- degree / inverse degree ----------------
__global__ __launch_bounds__(256) void k_deg(const int* __restrict__ rows,
                                             int* __restrict__ deg, int E) {
    int e = blockIdx.x * 256 + threadIdx.x;
    if (e < E) atomicAdd(&deg[rows[e]], 1);
}

__global__ __launch_bounds__(256) void k_invdeg(const int* __restrict__ deg,
                                                float* __restrict__ invdeg, int N) {
    int i = blockIdx.x * 256 + threadIdx.x;
    if (i < N) invdeg[i] = 1.0f / (float)max(deg[i], 1);
}

// ---------------- input layer: concat(emb, feat[1:]) @ W_in -> silu -> LN ----
__global__ __launch_bounds__(128) void k_input(
    const float* __restrict__ features, const float* __restrict__ emb,
    const float* __restrict__ W, const float* __restrict__ bias,
    const float* __restrict__ gain, const float* __restrict__ beta,
    float* __restrict__ x, int M)
{
    const int tid = threadIdx.x;
    const int node0 = blockIdx.x * NB;
    __shared__ float in_s[NB][160];
    __shared__ float ys[NB][129];
    __shared__ float mu_s[NB], inv_s[NB];

    const int nrows = min(NB, M - node0);
    for (int r = 0; r < nrows; ++r) {
        const float* feat = features + (size_t)(node0 + r) * 128;
        if (tid < 32) {
            int op = (int)feat[0];
            op = op < 0 ? 0 : (op > 127 ? 127 : op);
            in_s[r][tid] = emb[op * 32 + tid];
        }
        if (tid < 127) in_s[r][32 + tid] = feat[1 + tid];
    }
    __syncthreads();

    float acc[NB];
    #pragma unroll
    for (int r = 0; r < NB; ++r) acc[r] = bias[tid];
    for (int k = 0; k < 159; ++k) {
        float w = W[k * 128 + tid];
        #pragma unroll
        for (int r = 0; r < NB; ++r) acc[r] = fmaf(in_s[r][k], w, acc[r]);
    }
    #pragma unroll
    for (int r = 0; r < NB; ++r) {
        float a = acc[r];
        float y = a / (1.0f + __expf(-a));
        acc[r] = y;
        ys[r][tid] = y;
    }
    __syncthreads();
    {
        int row = tid >> 3;
        int c0 = (tid & 7) * 16;
        float s = 0.f, sq = 0.f;
        #pragma unroll
        for (int j = 0; j < 16; ++j) { float v = ys[row][c0 + j]; s += v; sq = fmaf(v, v, sq); }
        s += __shfl_down(s, 4); sq += __shfl_down(sq, 4);
        s += __shfl_down(s, 2); sq += __shfl_down(sq, 2);
        s += __shfl_down(s, 1); sq += __shfl_down(sq, 1);
        if ((tid & 7) == 0) {
            float mu = s * (1.0f / 128.0f);
            float var = sq * (1.0f / 128.0f) - mu * mu;
            mu_s[row] = mu;
            inv_s[row] = rsqrtf(var + LN_EPS);
        }
    }
    __syncthreads();
    const float g = gain[tid], bt = beta[tid];
    for (int r = 0; r < nrows; ++r)
        x[(size_t)(node0 + r) * 128 + tid] = (acc[r] - mu_s[r]) * inv_s[r] * g + bt;
}

// ---------------- message scatter: agg[rows[e]] += x[cols[e]] * invdeg[rows[e]]
__global__ __launch_bounds__(256) void k_scatter(
    const int* __restrict__ rows, const int* __restrict__ cols,
    const float* __restrict__ invdeg, const float* __restrict__ x,
    float* __restrict__ agg, int E, size_t strideB, int B)
{
    size_t gid = (size_t)blockIdx.x * 256 + threadIdx.x;
    size_t total = (size_t)E * 32;
    if (gid >= total) return;
    int e = (int)(gid >> 5);
    int lane = (int)(gid & 31);
    int rr = rows[e], cc = cols[e];
    float v = invdeg[rr];
    for (int b = 0; b < B; ++b) {
        const float4 xv = *(const float4*)(x + (size_t)b * strideB + (size_t)cc * 128 + lane * 4);
        float* dst = agg + (size_t)b * strideB + (size_t)rr * 128 + lane * 4;
        atomicAdd(dst + 0, xv.x * v);
        atomicAdd(dst + 1, xv.y * v);
        atomicAdd(dst + 2, xv.z * v);
        atomicAdd(dst + 3, xv.w * v);
    }
}

// ---------------- MP layer GEMM: LN(silu(agg @ W + b)) ----------------
__global__ __launch_bounds__(128) void k_mp(
    const float* __restrict__ agg,
    const float* __restrict__ W, const float* __restrict__ bias,
    const float* __restrict__ gain, const float* __restrict__ beta,
    float* __restrict__ x, int M)
{
    const int tid = threadIdx.x;
    const int node0 = blockIdx.x * NB;
    __shared__ float in_s[NB][128];
    __shared__ float ys[NB][129];
    __shared__ float mu_s[NB], inv_s[NB];

    const int nrows = min(NB, M - node0);
    for (int r = 0; r < nrows; ++r)
        in_s[r][tid] = agg[(size_t)(node0 + r) * 128 + tid];
    __syncthreads();

    float acc[NB];
    #pragma unroll
    for (int r = 0; r < NB; ++r) acc[r] = bias[tid];
    for (int k4 = 0; k4 < 128; k4 += 4) {
        float w0 = W[(k4 + 0) * 128 + tid];
        float w1 = W[(k4 + 1) * 128 + tid];
        float w2 = W[(k4 + 2) * 128 + tid];
        float w3 = W[(k4 + 3) * 128 + tid];
        #pragma unroll
        for (int r = 0; r < NB; ++r) {
            const float4 iv = *(const float4*)&in_s[r][k4];
            float a = acc[r];
            a = fmaf(iv.x, w0, a);
            a = fmaf(iv.y, w1, a);
            a = fmaf(iv.z, w2, a);
            a = fmaf(iv.w, w3, a);
            acc[r] = a;
        }
    }
    #pragma unroll
    for (int r = 0; r < NB; ++r) {
        float a = acc[r];
        float y = a / (1.0f + __expf(-a));
        acc[r] = y;
        ys[r][tid] = y;
    }
    __syncthreads();
    {
        int row = tid >> 3;
        int c0 = (tid & 7) * 16;
        float s = 0.f, sq = 0.f;
        #pragma unroll
        for (int j = 0; j < 16; ++j) { float v = ys[row][c0 + j]; s += v; sq = fmaf(v, v, sq); }
        s += __shfl_down(s, 4); sq += __shfl_down(sq, 4);
        s += __shfl_down(s, 2); sq += __shfl_down(sq, 2);
        s += __shfl_down(s, 1); sq += __shfl_down(sq, 1);
        if ((tid & 7) == 0) {
            float mu = s * (1.0f / 128.0f);
            float var = sq * (1.0f / 128.0f) - mu * mu;
            mu_s[row] = mu;
            inv_s[row] = rsqrtf(var + LN_EPS);
        }
    }
    __syncthreads();
    const float g = gain[tid], bt = beta[tid];
    for (int r = 0; r < nrows; ++r)
        x[(size_t)(node0 + r) * 128 + tid] = (acc[r] - mu_s[r]) * inv_s[r] * g + bt;
}

// ---------------- pooling ----------------
__global__ __launch_bounds__(128) void k_pool(
    const float* __restrict__ x, const int* __restrict__ lengths,
    float* __restrict__ pooled, int N, int B, int G, int SPLIT)
{
    int blk = blockIdx.x;
    int split = blk % SPLIT;
    int gb = blk / SPLIT;
    int b = gb % B, g = gb / B;
    int tid = threadIdx.x;
    int start = 0;
    for (int i = 0; i < g; ++i) start += lengths[i];
    int len = lengths[g];
    int chunk = (len + SPLIT - 1) / SPLIT;
    int n0 = start + split * chunk;
    int n1 = min(start + len, n0 + chunk);
    float s = 0.f;
    for (int n = n0; n < n1; ++n)
        s += x[((size_t)b * N + n) * 128 + tid];
    if (n1 > n0) atomicAdd(&pooled[(g * B + b) * 128 + tid], s);
}

__global__ __launch_bounds__(128) void k_proj(
    const float* __restrict__ pooled, const float* __restrict__ Wp,
    const float* __restrict__ bp, float* __restrict__ out, int GB)
{
    int gb = blockIdx.x;
    int tid = threadIdx.x;
    float v = pooled[gb * 128 + tid] * Wp[tid];
    v += __shfl_down(v, 32);
    v += __shfl_down(v, 16);
    v += __shfl_down(v, 8);
    v += __shfl_down(v, 4);
    v += __shfl_down(v, 2);
    v += __shfl_down(v, 1);
    __shared__ float red[2];
    if ((tid & 63) == 0) red[tid >> 6] = v;
    __syncthreads();
    if (tid == 0) out[gb] = red[0] + red[1] + bp[0];
}

// ---------------- host ----------------
extern "C" void kernel_launch(void* const* d_in, const int* in_sizes, int n_in,
                              void* d_out, int out_size, void* d_ws, size_t ws_size,
                              hipStream_t stream) {
    const float* features = (const float*)d_in[0];
    const int* edge_index = (const int*)d_in[1];
    const int* lengths    = (const int*)d_in[2];
    const float* emb      = (const float*)d_in[3];
    const float* W_in     = (const float*)d_in[4];
    const float* b_in     = (const float*)d_in[5];
    const float* g_in     = (const float*)d_in[6];
    const float* beta_in  = (const float*)d_in[7];
    const float* msg_W    = (const float*)d_in[8];
    const float* msg_b    = (const float*)d_in[9];
    const float* msg_g    = (const float*)d_in[10];
    const float* msg_beta = (const float*)d_in[11];
    const float* W_proj   = (const float*)d_in[12];
    const float* b_proj   = (const float*)d_in[13];
    float* out = (float*)d_out;

    const int E = in_sizes[1] / 2;
    const int G = in_sizes[2];
    const int B = out_size / G;
    const int C = in_sizes[5];           // 128
    const int F = 128;
    const int N = in_sizes[0] / (B * F);
    const int M = B * N;                 // flattened rows
    const int L = in_sizes[9] / C;       // 3 layers

    const int* rows = edge_index;
    const int* cols = edge_index + E;

    // workspace carve-up
    float* x      = (float*)d_ws;                    // M*C
    float* agg    = x + (size_t)M * C;               // M*C
    float* invdeg = agg + (size_t)M * C;             // N
    int*   deg    = (int*)(invdeg + N);              // N
    float* pooled = (float*)(deg + N);               // G*B*C

    // degree
    hipMemsetAsync(deg, 0, (size_t)N * sizeof(int), stream);
    k_deg<<<(E + 255) / 256, 256, 0, stream>>>(rows, deg, E);
    k_invdeg<<<(N + 255) / 256, 256, 0, stream>>>(deg, invdeg, N);

    // input layer
    k_input<<<(M + NB - 1) / NB, 128, 0, stream>>>(features, emb, W_in, b_in, g_in, beta_in, x, M);

    // message passing layers
    const size_t strideB = (size_t)N * C;
    for (int l = 0; l < L; ++l) {
        hipMemsetAsync(agg, 0, (size_t)M * C * sizeof(float), stream);
        size_t total = (size_t)E * 32;
        k_scatter<<<(int)((total + 255) / 256), 256, 0, stream>>>(rows, cols, invdeg, x, agg, E, strideB, B);
        k_mp<<<(M + NB - 1) / NB, 128, 0, stream>>>(agg, msg_W + (size_t)l * C * C, msg_b + (size_t)l * C,
                                                    msg_g + (size_t)l * C, msg_beta + (size_t)l * C, x, M);
    }

    // pooling + projection
    const int SPLIT = 64;
    hipMemsetAsync(pooled, 0, (size_t)G * B * C * sizeof(float), stream);
    k_pool<<<G * B * SPLIT, 128, 0, stream>>>(x, lengths, pooled, N, B, G, SPLIT);
    k_proj<<<G * B, 128, 0, stream>>>(pooled, W_proj, b_proj, out, G * B);
}

// Round 2
// 1057.817 us; speedup vs baseline: 4.6309x; 4.6309x over previous
//
#include <hip/hip_runtime.h>
#include <cstddef>

#define LN_EPS 1e-5f
constexpr int NB = 16;   // rows per GEMM block
constexpr int SCAN_T = 256, SCAN_V = 8, SCAN_ELEMS = SCAN_T * SCAN_V;

// ---------------- degree / inverse degree ----------------
__global__ __launch_bounds__(256) void k_deg(const int* __restrict__ rows,
                                             int* __restrict__ deg, int E) {
    int e = blockIdx.x * 256 + threadIdx.x;
    if (e < E) atomicAdd(&deg[rows[e]], 1);
}

__global__ __launch_bounds__(256) void k_invdeg(const int* __restrict__ deg,
                                                float* __restrict__ invdeg, int N) {
    int i = blockIdx.x * 256 + threadIdx.x;
    if (i < N) invdeg[i] = 1.0f / (float)max(deg[i], 1);
}

// ---------------- CSR build: hierarchical exclusive scan ----------------
__global__ __launch_bounds__(SCAN_T) void k_scan1(const int* __restrict__ deg,
                                                  int* __restrict__ row_ptr,
                                                  int* __restrict__ bsum, int N) {
    __shared__ int ts[SCAN_T];
    int t = threadIdx.x;
    int base = blockIdx.x * SCAN_ELEMS;
    int v[SCAN_V];
    int s = 0;
    #pragma unroll
    for (int j = 0; j < SCAN_V; ++j) {
        int i = base + t * SCAN_V + j;
        v[j] = (i < N) ? deg[i] : 0;
        s += v[j];
    }
    ts[t] = s;
    __syncthreads();
    for (int off = 1; off < SCAN_T; off <<= 1) {
        int val = (t >= off) ? ts[t - off] : 0;
        __syncthreads();
        ts[t] += val;
        __syncthreads();
    }
    int excl = (t > 0) ? ts[t - 1] : 0;
    #pragma unroll
    for (int j = 0; j < SCAN_V; ++j) {
        int i = base + t * SCAN_V + j;
        if (i < N) row_ptr[i] = excl;
        excl += v[j];
    }
    if (t == SCAN_T - 1) bsum[blockIdx.x] = ts[SCAN_T - 1];
}

__global__ void k_scan2(int* __restrict__ bsum, int nb, int* __restrict__ row_ptr, int N) {
    // single thread: exclusive scan of block sums (nb ~ 49)
    int run = 0;
    for (int i = 0; i < nb; ++i) {
        int v = bsum[i];
        bsum[i] = run;
        run += v;
    }
    row_ptr[N] = run;   // == E
}

__global__ __launch_bounds__(SCAN_T) void k_scan3(int* __restrict__ row_ptr,
                                                  const int* __restrict__ bsum, int N) {
    int add = bsum[blockIdx.x];
    int base = blockIdx.x * SCAN_ELEMS;
    #pragma unroll
    for (int j = 0; j < SCAN_V; ++j) {
        int i = base + threadIdx.x * SCAN_V + j;
        if (i < N) row_ptr[i] += add;
    }
}

__global__ __launch_bounds__(256) void k_copy_cursor(const int* __restrict__ row_ptr,
                                                     int* __restrict__ cursor, int N) {
    int i = blockIdx.x * 256 + threadIdx.x;
    if (i < N) cursor[i] = row_ptr[i];
}

__global__ __launch_bounds__(256) void k_bucket(const int* __restrict__ rows,
                                                const int* __restrict__ cols,
                                                int* __restrict__ cursor,
                                                int* __restrict__ col_sorted, int E) {
    int e = blockIdx.x * 256 + threadIdx.x;
    if (e < E) {
        int r = rows[e];
        int pos = atomicAdd(&cursor[r], 1);
        col_sorted[pos] = cols[e];
    }
}

// ---------------- input layer: concat(emb, feat[1:]) @ W_in -> silu -> LN ----
__global__ __launch_bounds__(128) void k_input(
    const float* __restrict__ features, const float* __restrict__ emb,
    const float* __restrict__ W, const float* __restrict__ bias,
    const float* __restrict__ gain, const float* __restrict__ beta,
    float* __restrict__ x, int M)
{
    const int tid = threadIdx.x;
    const int node0 = blockIdx.x * NB;
    __shared__ float in_s[NB][160];
    __shared__ float ys[NB][129];
    __shared__ float mu_s[NB], inv_s[NB];

    const int nrows = min(NB, M - node0);
    for (int r = 0; r < nrows; ++r) {
        const float* feat = features + (size_t)(node0 + r) * 128;
        if (tid < 32) {
            int op = (int)feat[0];
            op = op < 0 ? 0 : (op > 127 ? 127 : op);
            in_s[r][tid] = emb[op * 32 + tid];
        }
        if (tid < 127) in_s[r][32 + tid] = feat[1 + tid];
    }
    __syncthreads();

    float acc[NB];
    #pragma unroll
    for (int r = 0; r < NB; ++r) acc[r] = bias[tid];
    for (int k = 0; k < 159; ++k) {
        float w = W[k * 128 + tid];
        #pragma unroll
        for (int r = 0; r < NB; ++r) acc[r] = fmaf(in_s[r][k], w, acc[r]);
    }
    #pragma unroll
    for (int r = 0; r < NB; ++r) {
        float a = acc[r];
        float y = a / (1.0f + __expf(-a));
        acc[r] = y;
        ys[r][tid] = y;
    }
    __syncthreads();
    {
        int row = tid >> 3;
        int c0 = (tid & 7) * 16;
        float s = 0.f, sq = 0.f;
        #pragma unroll
        for (int j = 0; j < 16; ++j) { float v = ys[row][c0 + j]; s += v; sq = fmaf(v, v, sq); }
        s += __shfl_down(s, 4); sq += __shfl_down(sq, 4);
        s += __shfl_down(s, 2); sq += __shfl_down(sq, 2);
        s += __shfl_down(s, 1); sq += __shfl_down(sq, 1);
        if ((tid & 7) == 0) {
            float mu = s * (1.0f / 128.0f);
            float var = sq * (1.0f / 128.0f) - mu * mu;
            mu_s[row] = mu;
            inv_s[row] = rsqrtf(var + LN_EPS);
        }
    }
    __syncthreads();
    const float g = gain[tid], bt = beta[tid];
    for (int r = 0; r < nrows; ++r)
        x[(size_t)(node0 + r) * 128 + tid] = (acc[r] - mu_s[r]) * inv_s[r] * g + bt;
}

// ---------------- message gather (CSR): agg[r] = invdeg[r] * sum_e x[col[e]] --
__global__ __launch_bounds__(256) void k_gather(
    const int* __restrict__ row_ptr, const int* __restrict__ col_sorted,
    const float* __restrict__ invdeg, const float* __restrict__ x,
    float* __restrict__ agg, int N, size_t strideB, int B)
{
    int wave = (int)((blockIdx.x * 256 + threadIdx.x) >> 6);
    if (wave >= N) return;
    int lane = threadIdx.x & 63;
    int bh = lane >> 5;       // 0 or 1
    int l32 = lane & 31;
    int e0 = row_ptr[wave], e1 = row_ptr[wave + 1];
    float scale = invdeg[wave];
    for (int b = bh; b < B; b += 2) {
        const float* xb = x + (size_t)b * strideB;
        float4 acc = make_float4(0.f, 0.f, 0.f, 0.f);
        for (int e = e0; e < e1; ++e) {
            int cc = col_sorted[e];
            const float4 v = *(const float4*)(xb + (size_t)cc * 128 + l32 * 4);
            acc.x += v.x; acc.y += v.y; acc.z += v.z; acc.w += v.w;
        }
        float4* dst = (float4*)(agg + (size_t)b * strideB + (size_t)wave * 128 + l32 * 4);
        *dst = make_float4(acc.x * scale, acc.y * scale, acc.z * scale, acc.w * scale);
    }
}

// ---------------- MP layer GEMM: LN(silu(agg @ W + b)) ----------------
__global__ __launch_bounds__(128) void k_mp(
    const float* __restrict__ agg,
    const float* __restrict__ W, const float* __restrict__ bias,
    const float* __restrict__ gain, const float* __restrict__ beta,
    float* __restrict__ x, int M)
{
    const int tid = threadIdx.x;
    const int node0 = blockIdx.x * NB;
    __shared__ float in_s[NB][128];
    __shared__ float ys[NB][129];
    __shared__ float mu_s[NB], inv_s[NB];

    const int nrows = min(NB, M - node0);
    for (int r = 0; r < nrows; ++r)
        in_s[r][tid] = agg[(size_t)(node0 + r) * 128 + tid];
    __syncthreads();

    float acc[NB];
    #pragma unroll
    for (int r = 0; r < NB; ++r) acc[r] = bias[tid];
    for (int k4 = 0; k4 < 128; k4 += 4) {
        float w0 = W[(k4 + 0) * 128 + tid];
        float w1 = W[(k4 + 1) * 128 + tid];
        float w2 = W[(k4 + 2) * 128 + tid];
        float w3 = W[(k4 + 3) * 128 + tid];
        #pragma unroll
        for (int r = 0; r < NB; ++r) {
            const float4 iv = *(const float4*)&in_s[r][k4];
            float a = acc[r];
            a = fmaf(iv.x, w0, a);
            a = fmaf(iv.y, w1, a);
            a = fmaf(iv.z, w2, a);
            a = fmaf(iv.w, w3, a);
            acc[r] = a;
        }
    }
    #pragma unroll
    for (int r = 0; r < NB; ++r) {
        float a = acc[r];
        float y = a / (1.0f + __expf(-a));
        acc[r] = y;
        ys[r][tid] = y;
    }
    __syncthreads();
    {
        int row = tid >> 3;
        int c0 = (tid & 7) * 16;
        float s = 0.f, sq = 0.f;
        #pragma unroll
        for (int j = 0; j < 16; ++j) { float v = ys[row][c0 + j]; s += v; sq = fmaf(v, v, sq); }
        s += __shfl_down(s, 4); sq += __shfl_down(sq, 4);
        s += __shfl_down(s, 2); sq += __shfl_down(sq, 2);
        s += __shfl_down(s, 1); sq += __shfl_down(sq, 1);
        if ((tid & 7) == 0) {
            float mu = s * (1.0f / 128.0f);
            float var = sq * (1.0f / 128.0f) - mu * mu;
            mu_s[row] = mu;
            inv_s[row] = rsqrtf(var + LN_EPS);
        }
    }
    __syncthreads();
    const float g = gain[tid], bt = beta[tid];
    for (int r = 0; r < nrows; ++r)
        x[(size_t)(node0 + r) * 128 + tid] = (acc[r] - mu_s[r]) * inv_s[r] * g + bt;
}

// ---------------- pooling ----------------
__global__ __launch_bounds__(128) void k_pool(
    const float* __restrict__ x, const int* __restrict__ lengths,
    float* __restrict__ pooled, int N, int B, int G, int SPLIT)
{
    int blk = blockIdx.x;
    int split = blk % SPLIT;
    int gb = blk / SPLIT;
    int b = gb % B, g = gb / B;
    int tid = threadIdx.x;
    int start = 0;
    for (int i = 0; i < g; ++i) start += lengths[i];
    int len = lengths[g];
    int chunk = (len + SPLIT - 1) / SPLIT;
    int n0 = start + split * chunk;
    int n1 = min(start + len, n0 + chunk);
    float s = 0.f;
    for (int n = n0; n < n1; ++n)
        s += x[((size_t)b * N + n) * 128 + tid];
    if (n1 > n0) atomicAdd(&pooled[(g * B + b) * 128 + tid], s);
}

__global__ __launch_bounds__(128) void k_proj(
    const float* __restrict__ pooled, const float* __restrict__ Wp,
    const float* __restrict__ bp, float* __restrict__ out, int GB)
{
    int gb = blockIdx.x;
    int tid = threadIdx.x;
    float v = pooled[gb * 128 + tid] * Wp[tid];
    v += __shfl_down(v, 32);
    v += __shfl_down(v, 16);
    v += __shfl_down(v, 8);
    v += __shfl_down(v, 4);
    v += __shfl_down(v, 2);
    v += __shfl_down(v, 1);
    __shared__ float red[2];
    if ((tid & 63) == 0) red[tid >> 6] = v;
    __syncthreads();
    if (tid == 0) out[gb] = red[0] + red[1] + bp[0];
}

// ---------------- host ----------------
extern "C" void kernel_launch(void* const* d_in, const int* in_sizes, int n_in,
                              void* d_out, int out_size, void* d_ws, size_t ws_size,
                              hipStream_t stream) {
    const float* features = (const float*)d_in[0];
    const int* edge_index = (const int*)d_in[1];
    const int* lengths    = (const int*)d_in[2];
    const float* emb      = (const float*)d_in[3];
    const float* W_in     = (const float*)d_in[4];
    const float* b_in     = (const float*)d_in[5];
    const float* g_in     = (const float*)d_in[6];
    const float* beta_in  = (const float*)d_in[7];
    const float* msg_W    = (const float*)d_in[8];
    const float* msg_b    = (const float*)d_in[9];
    const float* msg_g    = (const float*)d_in[10];
    const float* msg_beta = (const float*)d_in[11];
    const float* W_proj   = (const float*)d_in[12];
    const float* b_proj   = (const float*)d_in[13];
    float* out = (float*)d_out;

    const int E = in_sizes[1] / 2;
    const int G = in_sizes[2];
    const int B = out_size / G;
    const int C = in_sizes[5];           // 128
    const int F = 128;
    const int N = in_sizes[0] / (B * F);
    const int M = B * N;                 // flattened rows
    const int L = in_sizes[9] / C;       // 3 layers

    const int* rows = edge_index;
    const int* cols = edge_index + E;

    // workspace carve-up
    float* x        = (float*)d_ws;                     // M*C floats
    float* agg      = x + (size_t)M * C;                // M*C floats
    float* invdeg   = agg + (size_t)M * C;              // N
    int*   deg      = (int*)(invdeg + N);               // N  (reused as cursor)
    float* pooled   = (float*)(deg + N);                // G*B*C
    int*   row_ptr  = (int*)(pooled + (size_t)G * B * C); // N+1
    int*   col_sorted = row_ptr + N + 1;                // E
    int*   bsum     = col_sorted + E;                   // ~64

    const int nb_scan = (N + SCAN_ELEMS - 1) / SCAN_ELEMS;

    // degree + CSR build
    hipMemsetAsync(deg, 0, (size_t)N * sizeof(int), stream);
    k_deg<<<(E + 255) / 256, 256, 0, stream>>>(rows, deg, E);
    k_invdeg<<<(N + 255) / 256, 256, 0, stream>>>(deg, invdeg, N);
    k_scan1<<<nb_scan, SCAN_T, 0, stream>>>(deg, row_ptr, bsum, N);
    k_scan2<<<1, 1, 0, stream>>>(bsum, nb_scan, row_ptr, N);
    k_scan3<<<nb_scan, SCAN_T, 0, stream>>>(row_ptr, bsum, N);
    k_copy_cursor<<<(N + 255) / 256, 256, 0, stream>>>(row_ptr, deg, N);
    k_bucket<<<(E + 255) / 256, 256, 0, stream>>>(rows, cols, deg, col_sorted, E);

    // input layer
    k_input<<<(M + NB - 1) / NB, 128, 0, stream>>>(features, emb, W_in, b_in, g_in, beta_in, x, M);

    // message passing layers
    const size_t strideB = (size_t)N * C;
    for (int l = 0; l < L; ++l) {
        k_gather<<<(N + 3) / 4, 256, 0, stream>>>(row_ptr, col_sorted, invdeg, x, agg, N, strideB, B);
        k_mp<<<(M + NB - 1) / NB, 128, 0, stream>>>(agg, msg_W + (size_t)l * C * C, msg_b + (size_t)l * C,
                                                    msg_g + (size_t)l * C, msg_beta + (size_t)l * C, x, M);
    }

    // pooling + projection
    const int SPLIT = 64;
    hipMemsetAsync(pooled, 0, (size_t)G * B * C * sizeof(float), stream);
    k_pool<<<G * B * SPLIT, 128, 0, stream>>>(x, lengths, pooled, N, B, G, SPLIT);
    k_proj<<<G * B, 128, 0, stream>>>(pooled, W_proj, b_proj, out, G * B);
}

// Round 3
// 489.733 us; speedup vs baseline: 10.0027x; 2.1600x over previous
//
#include <hip/hip_runtime.h>
#include <cstddef>

#define LN_EPS 1e-5f
typedef unsigned short u16;
typedef unsigned int u32;
typedef __attribute__((ext_vector_type(8))) short bf16x8;
typedef __attribute__((ext_vector_type(4))) float f32x4;

constexpr int SCAN_T = 256, SCAN_V = 8, SCAN_ELEMS = SCAN_T * SCAN_V;
constexpr int KP_IN = 168;   // padded K for input layer (K=160 used)
constexpr int KP_MP = 136;   // padded K for mp layers (K=128)

__device__ inline u16 f2bf(float f) {
    u32 u = __float_as_uint(f);
    u += 0x7FFFu + ((u >> 16) & 1u);
    return (u16)(u >> 16);
}
__device__ inline float bf2f(u16 h) { return __uint_as_float((u32)h << 16); }

// ---------------- degree / inverse degree ----------------
__global__ __launch_bounds__(256) void k_deg(const int* __restrict__ rows,
                                             int* __restrict__ deg, int E) {
    int e = blockIdx.x * 256 + threadIdx.x;
    if (e < E) atomicAdd(&deg[rows[e]], 1);
}

__global__ __launch_bounds__(256) void k_invdeg(const int* __restrict__ deg,
                                                float* __restrict__ invdeg, int N) {
    int i = blockIdx.x * 256 + threadIdx.x;
    if (i < N) invdeg[i] = 1.0f / (float)max(deg[i], 1);
}

// ---------------- CSR build ----------------
__global__ __launch_bounds__(SCAN_T) void k_scan1(const int* __restrict__ deg,
                                                  int* __restrict__ row_ptr,
                                                  int* __restrict__ bsum, int N) {
    __shared__ int ts[SCAN_T];
    int t = threadIdx.x;
    int base = blockIdx.x * SCAN_ELEMS;
    int v[SCAN_V];
    int s = 0;
    #pragma unroll
    for (int j = 0; j < SCAN_V; ++j) {
        int i = base + t * SCAN_V + j;
        v[j] = (i < N) ? deg[i] : 0;
        s += v[j];
    }
    ts[t] = s;
    __syncthreads();
    for (int off = 1; off < SCAN_T; off <<= 1) {
        int val = (t >= off) ? ts[t - off] : 0;
        __syncthreads();
        ts[t] += val;
        __syncthreads();
    }
    int excl = (t > 0) ? ts[t - 1] : 0;
    #pragma unroll
    for (int j = 0; j < SCAN_V; ++j) {
        int i = base + t * SCAN_V + j;
        if (i < N) row_ptr[i] = excl;
        excl += v[j];
    }
    if (t == SCAN_T - 1) bsum[blockIdx.x] = ts[SCAN_T - 1];
}

__global__ void k_scan2(int* __restrict__ bsum, int nb, int* __restrict__ row_ptr, int N) {
    int run = 0;
    for (int i = 0; i < nb; ++i) {
        int v = bsum[i];
        bsum[i] = run;
        run += v;
    }
    row_ptr[N] = run;
}

__global__ __launch_bounds__(SCAN_T) void k_scan3(int* __restrict__ row_ptr,
                                                  const int* __restrict__ bsum, int N) {
    int add = bsum[blockIdx.x];
    int base = blockIdx.x * SCAN_ELEMS;
    #pragma unroll
    for (int j = 0; j < SCAN_V; ++j) {
        int i = base + threadIdx.x * SCAN_V + j;
        if (i < N) row_ptr[i] += add;
    }
}

__global__ __launch_bounds__(256) void k_copy_cursor(const int* __restrict__ row_ptr,
                                                     int* __restrict__ cursor, int N) {
    int i = blockIdx.x * 256 + threadIdx.x;
    if (i < N) cursor[i] = row_ptr[i];
}

__global__ __launch_bounds__(256) void k_bucket(const int* __restrict__ rows,
                                                const int* __restrict__ cols,
                                                int* __restrict__ cursor,
                                                int* __restrict__ col_sorted, int E) {
    int e = blockIdx.x * 256 + threadIdx.x;
    if (e < E) {
        int r = rows[e];
        int pos = atomicAdd(&cursor[r], 1);
        col_sorted[pos] = cols[e];
    }
}

// ---------------- weight prep: transpose + bf16 + pad ----------------
__global__ __launch_bounds__(256) void k_wprep(const float* __restrict__ W_in,
                                               const float* __restrict__ msg_W,
                                               u16* __restrict__ Wt_in,
                                               u16* __restrict__ Wt_msg) {
    int idx = blockIdx.x * 256 + threadIdx.x;
    const int t1 = 128 * KP_IN;
    if (idx < t1) {
        int c = idx / KP_IN, k = idx % KP_IN;
        Wt_in[idx] = (k < 159) ? f2bf(W_in[k * 128 + c]) : (u16)0;
    } else {
        idx -= t1;
        if (idx < 3 * 128 * KP_MP) {
            int l = idx / (128 * KP_MP);
            int r = idx % (128 * KP_MP);
            int c = r / KP_MP, k = r % KP_MP;
            Wt_msg[idx] = (k < 128) ? f2bf(msg_W[l * 16384 + k * 128 + c]) : (u16)0;
        }
    }
}

// ---------------- input layer: MFMA bf16 ----------------
__global__ __launch_bounds__(256) void k_input_mfma(
    const float* __restrict__ features, const float* __restrict__ emb,
    const u16* __restrict__ Wt,
    const float* __restrict__ bias, const float* __restrict__ gain,
    const float* __restrict__ beta, u16* __restrict__ x, int M)
{
    __shared__ u16 A[64 * KP_IN];
    __shared__ u16 Wl[128 * KP_IN];
    __shared__ float bs[128], gs[128], bts[128];
    __shared__ int ops[64];
    const int tid = threadIdx.x;
    const int node0 = blockIdx.x * 64;

    {   // stage W^T
        const uint4* src = (const uint4*)Wt;
        uint4* dst = (uint4*)Wl;
        const int n16 = 128 * KP_IN * 2 / 16;
        for (int i = tid; i < n16; i += 256) dst[i] = src[i];
    }
    if (tid < 128) { bs[tid] = bias[tid]; gs[tid] = gain[tid]; bts[tid] = beta[tid]; }

    // phase 1: features -> A[32..159]
    for (int r4 = 0; r4 < 64; r4 += 16) {
        int r = r4 + (tid >> 4);
        int rg = min(node0 + r, M - 1);
        int c = (tid & 15) * 8;
        const float* fr = features + (size_t)rg * 128 + c;
        float4 v0 = *(const float4*)fr;
        float4 v1 = *(const float4*)(fr + 4);
        u16* Ar = A + r * KP_IN;
        if (c == 0) {
            int op = (int)v0.x;
            op = op < 0 ? 0 : (op > 127 ? 127 : op);
            ops[r] = op;
            Ar[32] = f2bf(v0.y); Ar[33] = f2bf(v0.z); Ar[34] = f2bf(v0.w);
            Ar[35] = f2bf(v1.x); Ar[36] = f2bf(v1.y); Ar[37] = f2bf(v1.z); Ar[38] = f2bf(v1.w);
        } else {
            int base = 31 + c;
            Ar[base + 0] = f2bf(v0.x); Ar[base + 1] = f2bf(v0.y);
            Ar[base + 2] = f2bf(v0.z); Ar[base + 3] = f2bf(v0.w);
            Ar[base + 4] = f2bf(v1.x); Ar[base + 5] = f2bf(v1.y);
            Ar[base + 6] = f2bf(v1.z); Ar[base + 7] = f2bf(v1.w);
            if (c == 120) Ar[159] = 0;
        }
    }
    __syncthreads();
    // phase 2: emb -> A[0..31]
    {
        int r = tid >> 2, c = (tid & 3) * 8;
        int op = ops[r];
        const float* er = emb + op * 32 + c;
        float4 v0 = *(const float4*)er;
        float4 v1 = *(const float4*)(er + 4);
        u16* Ar = A + r * KP_IN + c;
        Ar[0] = f2bf(v0.x); Ar[1] = f2bf(v0.y); Ar[2] = f2bf(v0.z); Ar[3] = f2bf(v0.w);
        Ar[4] = f2bf(v1.x); Ar[5] = f2bf(v1.y); Ar[6] = f2bf(v1.z); Ar[7] = f2bf(v1.w);
    }
    __syncthreads();

    const int lane = tid & 63, w = tid >> 6;
    const int arow = w * 16 + (lane & 15);
    const int kq = (lane >> 4) * 8;
    bf16x8 a[5];
    #pragma unroll
    for (int kt = 0; kt < 5; ++kt)
        a[kt] = *(const bf16x8*)&A[arow * KP_IN + kt * 32 + kq];
    f32x4 acc[8];
    #pragma unroll
    for (int t = 0; t < 8; ++t) {
        int bcol = t * 16 + (lane & 15);
        f32x4 c4 = {0.f, 0.f, 0.f, 0.f};
        #pragma unroll
        for (int kt = 0; kt < 5; ++kt) {
            bf16x8 b = *(const bf16x8*)&Wl[bcol * KP_IN + kt * 32 + kq];
            c4 = __builtin_amdgcn_mfma_f32_16x16x32_bf16(a[kt], b, c4, 0, 0, 0);
        }
        acc[t] = c4;
    }
    // bias + silu + LN
    float s[4] = {0, 0, 0, 0}, sq[4] = {0, 0, 0, 0};
    #pragma unroll
    for (int t = 0; t < 8; ++t) {
        int col = t * 16 + (lane & 15);
        #pragma unroll
        for (int i = 0; i < 4; ++i) {
            float aY = acc[t][i] + bs[col];
            float y = aY / (1.0f + __expf(-aY));
            acc[t][i] = y;
            s[i] += y;
            sq[i] = fmaf(y, y, sq[i]);
        }
    }
    #pragma unroll
    for (int m = 1; m <= 8; m <<= 1) {
        #pragma unroll
        for (int i = 0; i < 4; ++i) {
            s[i] += __shfl_xor(s[i], m);
            sq[i] += __shfl_xor(sq[i], m);
        }
    }
    float mu[4], inv[4];
    #pragma unroll
    for (int i = 0; i < 4; ++i) {
        mu[i] = s[i] * (1.0f / 128.0f);
        float var = sq[i] * (1.0f / 128.0f) - mu[i] * mu[i];
        inv[i] = rsqrtf(var + LN_EPS);
    }
    #pragma unroll
    for (int i = 0; i < 4; ++i) {
        int rg = node0 + w * 16 + (lane >> 4) * 4 + i;
        if (rg < M) {
            u16* xr = x + (size_t)rg * 128;
            #pragma unroll
            for (int t = 0; t < 8; ++t) {
                int col = t * 16 + (lane & 15);
                xr[col] = f2bf((acc[t][i] - mu[i]) * inv[i] * gs[col] + bts[col]);
            }
        }
    }
}

// ---------------- mp layer: MFMA bf16 ----------------
__global__ __launch_bounds__(256) void k_mp_mfma(
    const u16* __restrict__ agg, const u16* __restrict__ Wt,
    const float* __restrict__ bias, const float* __restrict__ gain,
    const float* __restrict__ beta, u16* __restrict__ x, int M)
{
    __shared__ u16 A[64 * KP_MP];
    __shared__ u16 Wl[128 * KP_MP];
    __shared__ float bs[128], gs[128], bts[128];
    const int tid = threadIdx.x;
    const int node0 = blockIdx.x * 64;

    {   // stage W^T
        const uint4* src = (const uint4*)Wt;
        uint4* dst = (uint4*)Wl;
        const int n16 = 128 * KP_MP * 2 / 16;
        for (int i = tid; i < n16; i += 256) dst[i] = src[i];
    }
    if (tid < 128) { bs[tid] = bias[tid]; gs[tid] = gain[tid]; bts[tid] = beta[tid]; }
    {   // stage A rows (bf16, 256B/row, 4 threads/row x 64B)
        int r = tid >> 2, q = tid & 3;
        int rg = min(node0 + r, M - 1);
        const uint4* src = (const uint4*)(agg + (size_t)rg * 128) + q * 4;
        uint4* dst = (uint4*)(A + r * KP_MP) + q * 4;
        dst[0] = src[0]; dst[1] = src[1]; dst[2] = src[2]; dst[3] = src[3];
    }
    __syncthreads();

    const int lane = tid & 63, w = tid >> 6;
    const int arow = w * 16 + (lane & 15);
    const int kq = (lane >> 4) * 8;
    bf16x8 a[4];
    #pragma unroll
    for (int kt = 0; kt < 4; ++kt)
        a[kt] = *(const bf16x8*)&A[arow * KP_MP + kt * 32 + kq];
    f32x4 acc[8];
    #pragma unroll
    for (int t = 0; t < 8; ++t) {
        int bcol = t * 16 + (lane & 15);
        f32x4 c4 = {0.f, 0.f, 0.f, 0.f};
        #pragma unroll
        for (int kt = 0; kt < 4; ++kt) {
            bf16x8 b = *(const bf16x8*)&Wl[bcol * KP_MP + kt * 32 + kq];
            c4 = __builtin_amdgcn_mfma_f32_16x16x32_bf16(a[kt], b, c4, 0, 0, 0);
        }
        acc[t] = c4;
    }
    float s[4] = {0, 0, 0, 0}, sq[4] = {0, 0, 0, 0};
    #pragma unroll
    for (int t = 0; t < 8; ++t) {
        int col = t * 16 + (lane & 15);
        #pragma unroll
        for (int i = 0; i < 4; ++i) {
            float aY = acc[t][i] + bs[col];
            float y = aY / (1.0f + __expf(-aY));
            acc[t][i] = y;
            s[i] += y;
            sq[i] = fmaf(y, y, sq[i]);
        }
    }
    #pragma unroll
    for (int m = 1; m <= 8; m <<= 1) {
        #pragma unroll
        for (int i = 0; i < 4; ++i) {
            s[i] += __shfl_xor(s[i], m);
            sq[i] += __shfl_xor(sq[i], m);
        }
    }
    float mu[4], inv[4];
    #pragma unroll
    for (int i = 0; i < 4; ++i) {
        mu[i] = s[i] * (1.0f / 128.0f);
        float var = sq[i] * (1.0f / 128.0f) - mu[i] * mu[i];
        inv[i] = rsqrtf(var + LN_EPS);
    }
    #pragma unroll
    for (int i = 0; i < 4; ++i) {
        int rg = node0 + w * 16 + (lane >> 4) * 4 + i;
        if (rg < M) {
            u16* xr = x + (size_t)rg * 128;
            #pragma unroll
            for (int t = 0; t < 8; ++t) {
                int col = t * 16 + (lane & 15);
                xr[col] = f2bf((acc[t][i] - mu[i]) * inv[i] * gs[col] + bts[col]);
            }
        }
    }
}

// ---------------- gather (bf16): one wave per (row, b) ----------------
__global__ __launch_bounds__(256) void k_gather(
    const int* __restrict__ row_ptr, const int* __restrict__ col_sorted,
    const float* __restrict__ invdeg, const u16* __restrict__ x,
    u16* __restrict__ agg, int N, int B)
{
    int wid = (int)((blockIdx.x * 256 + threadIdx.x) >> 6);
    if (wid >= N * B) return;
    int lane = threadIdx.x & 63;
    int row = wid / B;
    int b = wid - row * B;
    int e0 = row_ptr[row], e1 = row_ptr[row + 1];
    float scale = invdeg[row];
    const u32* xb = (const u32*)x + (size_t)b * N * 64;
    float ax0 = 0.f, ay0 = 0.f, ax1 = 0.f, ay1 = 0.f;
    int e = e0;
    for (; e + 1 < e1; e += 2) {
        int c0 = col_sorted[e], c1 = col_sorted[e + 1];
        u32 v0 = xb[(size_t)c0 * 64 + lane];
        u32 v1 = xb[(size_t)c1 * 64 + lane];
        ax0 += bf2f((u16)(v0 & 0xFFFF)); ay0 += bf2f((u16)(v0 >> 16));
        ax1 += bf2f((u16)(v1 & 0xFFFF)); ay1 += bf2f((u16)(v1 >> 16));
    }
    if (e < e1) {
        u32 v = xb[(size_t)col_sorted[e] * 64 + lane];
        ax0 += bf2f((u16)(v & 0xFFFF)); ay0 += bf2f((u16)(v >> 16));
    }
    float rx = (ax0 + ax1) * scale, ry = (ay0 + ay1) * scale;
    u32 p = (u32)f2bf(rx) | ((u32)f2bf(ry) << 16);
    ((u32*)agg)[(size_t)wid * 0 + (size_t)(b * N + row) * 64 + lane] = p;
}

// ---------------- pooling ----------------
__global__ __launch_bounds__(64) void k_pool(
    const u16* __restrict__ x, const int* __restrict__ lengths,
    float* __restrict__ pooled, int N, int B, int G, int SPLIT)
{
    int blk = blockIdx.x;
    int split = blk % SPLIT;
    int gb = blk / SPLIT;
    int b = gb % B, g = gb / B;
    int lane = threadIdx.x;
    int start = 0;
    for (int i = 0; i < g; ++i) start += lengths[i];
    int len = lengths[g];
    int chunk = (len + SPLIT - 1) / SPLIT;
    int n0 = start + split * chunk;
    int n1 = min(start + len, n0 + chunk);
    const u32* xb = (const u32*)x + (size_t)b * N * 64;
    float sx = 0.f, sy = 0.f;
    for (int n = n0; n < n1; ++n) {
        u32 v = xb[(size_t)n * 64 + lane];
        sx += bf2f((u16)(v & 0xFFFF));
        sy += bf2f((u16)(v >> 16));
    }
    if (n1 > n0) {
        atomicAdd(&pooled[(g * B + b) * 128 + lane * 2 + 0], sx);
        atomicAdd(&pooled[(g * B + b) * 128 + lane * 2 + 1], sy);
    }
}

__global__ __launch_bounds__(128) void k_proj(
    const float* __restrict__ pooled, const float* __restrict__ Wp,
    const float* __restrict__ bp, float* __restrict__ out, int GB)
{
    int gb = blockIdx.x;
    int tid = threadIdx.x;
    float v = pooled[gb * 128 + tid] * Wp[tid];
    v += __shfl_down(v, 32);
    v += __shfl_down(v, 16);
    v += __shfl_down(v, 8);
    v += __shfl_down(v, 4);
    v += __shfl_down(v, 2);
    v += __shfl_down(v, 1);
    __shared__ float red[2];
    if ((tid & 63) == 0) red[tid >> 6] = v;
    __syncthreads();
    if (tid == 0) out[gb] = red[0] + red[1] + bp[0];
}

// ---------------- host ----------------
extern "C" void kernel_launch(void* const* d_in, const int* in_sizes, int n_in,
                              void* d_out, int out_size, void* d_ws, size_t ws_size,
                              hipStream_t stream) {
    const float* features = (const float*)d_in[0];
    const int* edge_index = (const int*)d_in[1];
    const int* lengths    = (const int*)d_in[2];
    const float* emb      = (const float*)d_in[3];
    const float* W_in     = (const float*)d_in[4];
    const float* b_in     = (const float*)d_in[5];
    const float* g_in     = (const float*)d_in[6];
    const float* beta_in  = (const float*)d_in[7];
    const float* msg_W    = (const float*)d_in[8];
    const float* msg_b    = (const float*)d_in[9];
    const float* msg_g    = (const float*)d_in[10];
    const float* msg_beta = (const float*)d_in[11];
    const float* W_proj   = (const float*)d_in[12];
    const float* b_proj   = (const float*)d_in[13];
    float* out = (float*)d_out;

    const int E = in_sizes[1] / 2;
    const int G = in_sizes[2];
    const int B = out_size / G;
    const int C = in_sizes[5];           // 128
    const int F = 128;
    const int N = in_sizes[0] / (B * F);
    const int M = B * N;
    const int L = in_sizes[9] / C;       // 3

    const int* rows = edge_index;
    const int* cols = edge_index + E;

    // workspace carve-up (all offsets 16B-aligned)
    u16* x_bf   = (u16*)d_ws;                               // M*128
    u16* agg_bf = x_bf + (size_t)M * 128;                   // M*128
    u16* Wt_in  = agg_bf + (size_t)M * 128;                 // 128*KP_IN
    u16* Wt_msg = Wt_in + 128 * KP_IN;                      // 3*128*KP_MP
    float* invdeg = (float*)(Wt_msg + 3 * 128 * KP_MP);     // N
    int*   deg    = (int*)(invdeg + N);                     // N
    float* pooled = (float*)(deg + N);                      // G*B*128
    int*   row_ptr = (int*)(pooled + (size_t)G * B * 128);  // N+1
    int*   col_sorted = row_ptr + N + 1;                    // E
    int*   bsum   = col_sorted + E;

    const int nb_scan = (N + SCAN_ELEMS - 1) / SCAN_ELEMS;

    // weight prep
    {
        int total = 128 * KP_IN + 3 * 128 * KP_MP;
        k_wprep<<<(total + 255) / 256, 256, 0, stream>>>(W_in, msg_W, Wt_in, Wt_msg);
    }

    // degree + CSR
    hipMemsetAsync(deg, 0, (size_t)N * sizeof(int), stream);
    k_deg<<<(E + 255) / 256, 256, 0, stream>>>(rows, deg, E);
    k_invdeg<<<(N + 255) / 256, 256, 0, stream>>>(deg, invdeg, N);
    k_scan1<<<nb_scan, SCAN_T, 0, stream>>>(deg, row_ptr, bsum, N);
    k_scan2<<<1, 1, 0, stream>>>(bsum, nb_scan, row_ptr, N);
    k_scan3<<<nb_scan, SCAN_T, 0, stream>>>(row_ptr, bsum, N);
    k_copy_cursor<<<(N + 255) / 256, 256, 0, stream>>>(row_ptr, deg, N);
    k_bucket<<<(E + 255) / 256, 256, 0, stream>>>(rows, cols, deg, col_sorted, E);

    // input layer
    k_input_mfma<<<(M + 63) / 64, 256, 0, stream>>>(features, emb, Wt_in,
                                                    b_in, g_in, beta_in, x_bf, M);

    // mp layers
    for (int l = 0; l < L; ++l) {
        int waves = N * B;
        k_gather<<<(waves * 64 + 255) / 256, 256, 0, stream>>>(row_ptr, col_sorted, invdeg,
                                                               x_bf, agg_bf, N, B);
        k_mp_mfma<<<(M + 63) / 64, 256, 0, stream>>>(agg_bf, Wt_msg + (size_t)l * 128 * KP_MP,
                                                     msg_b + (size_t)l * C, msg_g + (size_t)l * C,
                                                     msg_beta + (size_t)l * C, x_bf, M);
    }

    // pooling + projection
    const int SPLIT = 64;
    hipMemsetAsync(pooled, 0, (size_t)G * B * 128 * sizeof(float), stream);
    k_pool<<<G * B * SPLIT, 64, 0, stream>>>(x_bf, lengths, pooled, N, B, G, SPLIT);
    k_proj<<<G * B, 128, 0, stream>>>(pooled, W_proj, b_proj, out, G * B);
}

// Round 4
// 420.844 us; speedup vs baseline: 11.6401x; 1.1637x over previous
//
#include <hip/hip_runtime.h>
#include <cstddef>

#define LN_EPS 1e-5f
typedef unsigned short u16;
typedef unsigned int u32;
typedef __attribute__((ext_vector_type(8))) short bf16x8;
typedef __attribute__((ext_vector_type(4))) float f32x4;

constexpr int SCAN_T = 256, SCAN_V = 8, SCAN_ELEMS = SCAN_T * SCAN_V;
constexpr int KP_IN = 168;   // K=160 (feat 0..127 incl zero-weight feat0, emb 128..159), pad->168
constexpr int KP_MP = 136;   // K=128, pad->136

__device__ inline u16 f2bf(float f) {
    u32 u = __float_as_uint(f);
    u += 0x7FFFu + ((u >> 16) & 1u);
    return (u16)(u >> 16);
}
__device__ inline float bf2f(u16 h) { return __uint_as_float((u32)h << 16); }

// ---------------- degree / inverse degree ----------------
__global__ __launch_bounds__(256) void k_deg(const int* __restrict__ rows,
                                             int* __restrict__ deg, int E) {
    int e = blockIdx.x * 256 + threadIdx.x;
    if (e < E) atomicAdd(&deg[rows[e]], 1);
}

__global__ __launch_bounds__(256) void k_invdeg(const int* __restrict__ deg,
                                                float* __restrict__ invdeg, int N) {
    int i = blockIdx.x * 256 + threadIdx.x;
    if (i < N) invdeg[i] = 1.0f / (float)max(deg[i], 1);
}

// ---------------- CSR build ----------------
__global__ __launch_bounds__(SCAN_T) void k_scan1(const int* __restrict__ deg,
                                                  int* __restrict__ row_ptr,
                                                  int* __restrict__ bsum, int N) {
    __shared__ int ts[SCAN_T];
    int t = threadIdx.x;
    int base = blockIdx.x * SCAN_ELEMS;
    int v[SCAN_V];
    int s = 0;
    #pragma unroll
    for (int j = 0; j < SCAN_V; ++j) {
        int i = base + t * SCAN_V + j;
        v[j] = (i < N) ? deg[i] : 0;
        s += v[j];
    }
    ts[t] = s;
    __syncthreads();
    for (int off = 1; off < SCAN_T; off <<= 1) {
        int val = (t >= off) ? ts[t - off] : 0;
        __syncthreads();
        ts[t] += val;
        __syncthreads();
    }
    int excl = (t > 0) ? ts[t - 1] : 0;
    #pragma unroll
    for (int j = 0; j < SCAN_V; ++j) {
        int i = base + t * SCAN_V + j;
        if (i < N) row_ptr[i] = excl;
        excl += v[j];
    }
    if (t == SCAN_T - 1) bsum[blockIdx.x] = ts[SCAN_T - 1];
}

__global__ void k_scan2(int* __restrict__ bsum, int nb, int* __restrict__ row_ptr, int N) {
    int run = 0;
    for (int i = 0; i < nb; ++i) {
        int v = bsum[i];
        bsum[i] = run;
        run += v;
    }
    row_ptr[N] = run;
}

__global__ __launch_bounds__(SCAN_T) void k_scan3(int* __restrict__ row_ptr,
                                                  const int* __restrict__ bsum, int N) {
    int add = bsum[blockIdx.x];
    int base = blockIdx.x * SCAN_ELEMS;
    #pragma unroll
    for (int j = 0; j < SCAN_V; ++j) {
        int i = base + threadIdx.x * SCAN_V + j;
        if (i < N) row_ptr[i] += add;
    }
}

__global__ __launch_bounds__(256) void k_copy_cursor(const int* __restrict__ row_ptr,
                                                     int* __restrict__ cursor, int N) {
    int i = blockIdx.x * 256 + threadIdx.x;
    if (i < N) cursor[i] = row_ptr[i];
}

__global__ __launch_bounds__(256) void k_bucket(const int* __restrict__ rows,
                                                const int* __restrict__ cols,
                                                int* __restrict__ cursor,
                                                int* __restrict__ col_sorted, int E) {
    int e = blockIdx.x * 256 + threadIdx.x;
    if (e < E) {
        int r = rows[e];
        int pos = atomicAdd(&cursor[r], 1);
        col_sorted[pos] = cols[e];
    }
}

// ---------------- weight prep: transpose + bf16 + pad + K-reorder ------------
__global__ __launch_bounds__(256) void k_wprep(const float* __restrict__ W_in,
                                               const float* __restrict__ msg_W,
                                               u16* __restrict__ Wt_in,
                                               u16* __restrict__ Wt_msg) {
    int idx = blockIdx.x * 256 + threadIdx.x;
    const int t1 = 128 * KP_IN;
    if (idx < t1) {
        int c = idx / KP_IN, k = idx % KP_IN;
        float v = 0.f;
        if (k >= 1 && k < 128)       v = W_in[(31 + k) * 128 + c];  // feat[k]
        else if (k >= 128 && k < 160) v = W_in[(k - 128) * 128 + c]; // emb[k-128]
        Wt_in[idx] = f2bf(v);
    } else {
        idx -= t1;
        if (idx < 3 * 128 * KP_MP) {
            int l = idx / (128 * KP_MP);
            int r = idx % (128 * KP_MP);
            int c = r / KP_MP, k = r % KP_MP;
            Wt_msg[idx] = (k < 128) ? f2bf(msg_W[l * 16384 + k * 128 + c]) : (u16)0;
        }
    }
}

// ---------------- input layer: MFMA bf16, grid-stride tiles ----------------
__global__ __launch_bounds__(256) void k_input_mfma(
    const float* __restrict__ features, const float* __restrict__ emb,
    const u16* __restrict__ Wt,
    const float* __restrict__ bias, const float* __restrict__ gain,
    const float* __restrict__ beta, u16* __restrict__ x, int M, int ntiles)
{
    __shared__ u16 A[64 * KP_IN];
    __shared__ u16 Wl[128 * KP_IN];
    __shared__ float bs[128], gs[128], bts[128];
    __shared__ int ops[64];
    const int tid = threadIdx.x;

    {   // stage W^T once per block
        const uint4* src = (const uint4*)Wt;
        uint4* dst = (uint4*)Wl;
        const int n16 = 128 * KP_IN / 8;
        for (int i = tid; i < n16; i += 256) dst[i] = src[i];
    }
    if (tid < 128) { bs[tid] = bias[tid]; gs[tid] = gain[tid]; bts[tid] = beta[tid]; }

    const int lane = tid & 63, w = tid >> 6;
    const int r = tid >> 2, q = tid & 3;

    for (int tile = blockIdx.x; tile < ntiles; tile += gridDim.x) {
        const int node0 = tile * 64;
        __syncthreads();
        // phase 1: features row r, cols q*32..+31 -> A[r][q*32..] (k=0..127)
        {
            int rg = min(node0 + r, M - 1);
            const float* fr = features + (size_t)rg * 128 + q * 32;
            u32 pk[16];
            #pragma unroll
            for (int j = 0; j < 8; ++j) {
                float4 v = ((const float4*)fr)[j];
                pk[2 * j]     = (u32)f2bf(v.x) | ((u32)f2bf(v.y) << 16);
                pk[2 * j + 1] = (u32)f2bf(v.z) | ((u32)f2bf(v.w) << 16);
            }
            if (q == 0) {
                int op = (int)fr[0];
                op = op < 0 ? 0 : (op > 127 ? 127 : op);
                ops[r] = op;
            }
            uint4* dst = (uint4*)&A[r * KP_IN + q * 32];
            #pragma unroll
            for (int j = 0; j < 4; ++j)
                dst[j] = make_uint4(pk[4 * j], pk[4 * j + 1], pk[4 * j + 2], pk[4 * j + 3]);
        }
        __syncthreads();
        // phase 2: emb -> A[r][128 + q*8 ..]
        {
            const float* er = emb + ops[r] * 32 + q * 8;
            float4 v0 = ((const float4*)er)[0];
            float4 v1 = ((const float4*)er)[1];
            uint4 wv;
            wv.x = (u32)f2bf(v0.x) | ((u32)f2bf(v0.y) << 16);
            wv.y = (u32)f2bf(v0.z) | ((u32)f2bf(v0.w) << 16);
            wv.z = (u32)f2bf(v1.x) | ((u32)f2bf(v1.y) << 16);
            wv.w = (u32)f2bf(v1.z) | ((u32)f2bf(v1.w) << 16);
            *(uint4*)&A[r * KP_IN + 128 + q * 8] = wv;
        }
        __syncthreads();

        // MFMA
        const int arow = w * 16 + (lane & 15);
        const int kq = (lane >> 4) * 8;
        bf16x8 a[5];
        #pragma unroll
        for (int kt = 0; kt < 5; ++kt)
            a[kt] = *(const bf16x8*)&A[arow * KP_IN + kt * 32 + kq];
        f32x4 acc[8];
        #pragma unroll
        for (int t = 0; t < 8; ++t) {
            int bcol = t * 16 + (lane & 15);
            f32x4 c4 = {0.f, 0.f, 0.f, 0.f};
            #pragma unroll
            for (int kt = 0; kt < 5; ++kt) {
                bf16x8 b = *(const bf16x8*)&Wl[bcol * KP_IN + kt * 32 + kq];
                c4 = __builtin_amdgcn_mfma_f32_16x16x32_bf16(a[kt], b, c4, 0, 0, 0);
            }
            acc[t] = c4;
        }
        // bias + silu + LN
        float s[4] = {0, 0, 0, 0}, sq[4] = {0, 0, 0, 0};
        #pragma unroll
        for (int t = 0; t < 8; ++t) {
            int col = t * 16 + (lane & 15);
            #pragma unroll
            for (int i = 0; i < 4; ++i) {
                float aY = acc[t][i] + bs[col];
                float y = aY / (1.0f + __expf(-aY));
                acc[t][i] = y;
                s[i] += y;
                sq[i] = fmaf(y, y, sq[i]);
            }
        }
        #pragma unroll
        for (int m = 1; m <= 8; m <<= 1) {
            #pragma unroll
            for (int i = 0; i < 4; ++i) {
                s[i] += __shfl_xor(s[i], m);
                sq[i] += __shfl_xor(sq[i], m);
            }
        }
        #pragma unroll
        for (int i = 0; i < 4; ++i) {
            float mu = s[i] * (1.0f / 128.0f);
            float var = sq[i] * (1.0f / 128.0f) - mu * mu;
            float inv = rsqrtf(var + LN_EPS);
            int rg = node0 + w * 16 + (lane >> 4) * 4 + i;
            if (rg < M) {
                u16* xr = x + (size_t)rg * 128;
                #pragma unroll
                for (int t = 0; t < 8; ++t) {
                    int col = t * 16 + (lane & 15);
                    xr[col] = f2bf((acc[t][i] - mu) * inv * gs[col] + bts[col]);
                }
            }
        }
    }
}

// ---------------- fused mp layer: CSR gather -> LDS -> MFMA ----------------
__global__ __launch_bounds__(256) void k_mp_mfma(
    const int* __restrict__ row_ptr, const int* __restrict__ col_sorted,
    const float* __restrict__ invdeg, const u16* __restrict__ xin,
    const u16* __restrict__ Wt, const float* __restrict__ bias,
    const float* __restrict__ gain, const float* __restrict__ beta,
    u16* __restrict__ xout, int N, int M, int ntiles)
{
    __shared__ u16 A[64 * KP_MP];
    __shared__ u16 Wl[128 * KP_MP];
    __shared__ float bs[128], gs[128], bts[128];
    const int tid = threadIdx.x;

    {   // stage W^T once per block
        const uint4* src = (const uint4*)Wt;
        uint4* dst = (uint4*)Wl;
        const int n16 = 128 * KP_MP / 8;
        for (int i = tid; i < n16; i += 256) dst[i] = src[i];
    }
    if (tid < 128) { bs[tid] = bias[tid]; gs[tid] = gain[tid]; bts[tid] = beta[tid]; }

    const int lane = tid & 63, w = tid >> 6;
    const int r = tid >> 2, q = tid & 3;

    for (int tile = blockIdx.x; tile < ntiles; tile += gridDim.x) {
        const int node0 = tile * 64;
        __syncthreads();
        // gather: 4 threads/row, 32 cols (16 u32) each, f32 accumulate
        {
            int rg = min(node0 + r, M - 1);
            int b = rg / N;
            int nrow = rg - b * N;
            int e0 = row_ptr[nrow], e1 = row_ptr[nrow + 1];
            float sc = invdeg[nrow];
            const u32* xb = (const u32*)xin + (size_t)b * N * 64 + q * 16;
            float acc[32];
            #pragma unroll
            for (int j = 0; j < 32; ++j) acc[j] = 0.f;
            for (int e = e0; e < e1; ++e) {
                const uint4* s4 = (const uint4*)(xb + (size_t)col_sorted[e] * 64);
                uint4 u0 = s4[0], u1 = s4[1], u2 = s4[2], u3 = s4[3];
                u32 vv[16] = {u0.x, u0.y, u0.z, u0.w, u1.x, u1.y, u1.z, u1.w,
                              u2.x, u2.y, u2.z, u2.w, u3.x, u3.y, u3.z, u3.w};
                #pragma unroll
                for (int j = 0; j < 16; ++j) {
                    acc[2 * j]     += bf2f((u16)(vv[j] & 0xFFFF));
                    acc[2 * j + 1] += bf2f((u16)(vv[j] >> 16));
                }
            }
            u32 pk[16];
            #pragma unroll
            for (int j = 0; j < 16; ++j)
                pk[j] = (u32)f2bf(acc[2 * j] * sc) | ((u32)f2bf(acc[2 * j + 1] * sc) << 16);
            uint4* dst = (uint4*)&A[r * KP_MP + q * 32];
            #pragma unroll
            for (int j = 0; j < 4; ++j)
                dst[j] = make_uint4(pk[4 * j], pk[4 * j + 1], pk[4 * j + 2], pk[4 * j + 3]);
        }
        __syncthreads();

        // MFMA
        const int arow = w * 16 + (lane & 15);
        const int kq = (lane >> 4) * 8;
        bf16x8 a[4];
        #pragma unroll
        for (int kt = 0; kt < 4; ++kt)
            a[kt] = *(const bf16x8*)&A[arow * KP_MP + kt * 32 + kq];
        f32x4 acc[8];
        #pragma unroll
        for (int t = 0; t < 8; ++t) {
            int bcol = t * 16 + (lane & 15);
            f32x4 c4 = {0.f, 0.f, 0.f, 0.f};
            #pragma unroll
            for (int kt = 0; kt < 4; ++kt) {
                bf16x8 b = *(const bf16x8*)&Wl[bcol * KP_MP + kt * 32 + kq];
                c4 = __builtin_amdgcn_mfma_f32_16x16x32_bf16(a[kt], b, c4, 0, 0, 0);
            }
            acc[t] = c4;
        }
        float s[4] = {0, 0, 0, 0}, sq[4] = {0, 0, 0, 0};
        #pragma unroll
        for (int t = 0; t < 8; ++t) {
            int col = t * 16 + (lane & 15);
            #pragma unroll
            for (int i = 0; i < 4; ++i) {
                float aY = acc[t][i] + bs[col];
                float y = aY / (1.0f + __expf(-aY));
                acc[t][i] = y;
                s[i] += y;
                sq[i] = fmaf(y, y, sq[i]);
            }
        }
        #pragma unroll
        for (int m = 1; m <= 8; m <<= 1) {
            #pragma unroll
            for (int i = 0; i < 4; ++i) {
                s[i] += __shfl_xor(s[i], m);
                sq[i] += __shfl_xor(sq[i], m);
            }
        }
        #pragma unroll
        for (int i = 0; i < 4; ++i) {
            float mu = s[i] * (1.0f / 128.0f);
            float var = sq[i] * (1.0f / 128.0f) - mu * mu;
            float inv = rsqrtf(var + LN_EPS);
            int rg = node0 + w * 16 + (lane >> 4) * 4 + i;
            if (rg < M) {
                u16* xr = xout + (size_t)rg * 128;
                #pragma unroll
                for (int t = 0; t < 8; ++t) {
                    int col = t * 16 + (lane & 15);
                    xr[col] = f2bf((acc[t][i] - mu) * inv * gs[col] + bts[col]);
                }
            }
        }
    }
}

// ---------------- pooling ----------------
__global__ __launch_bounds__(64) void k_pool(
    const u16* __restrict__ x, const int* __restrict__ lengths,
    float* __restrict__ pooled, int N, int B, int G, int SPLIT)
{
    int blk = blockIdx.x;
    int split = blk % SPLIT;
    int gb = blk / SPLIT;
    int b = gb % B, g = gb / B;
    int lane = threadIdx.x;
    int start = 0;
    for (int i = 0; i < g; ++i) start += lengths[i];
    int len = lengths[g];
    int chunk = (len + SPLIT - 1) / SPLIT;
    int n0 = start + split * chunk;
    int n1 = min(start + len, n0 + chunk);
    const u32* xb = (const u32*)x + (size_t)b * N * 64;
    float sx = 0.f, sy = 0.f;
    for (int n = n0; n < n1; ++n) {
        u32 v = xb[(size_t)n * 64 + lane];
        sx += bf2f((u16)(v & 0xFFFF));
        sy += bf2f((u16)(v >> 16));
    }
    if (n1 > n0) {
        atomicAdd(&pooled[(g * B + b) * 128 + lane * 2 + 0], sx);
        atomicAdd(&pooled[(g * B + b) * 128 + lane * 2 + 1], sy);
    }
}

__global__ __launch_bounds__(128) void k_proj(
    const float* __restrict__ pooled, const float* __restrict__ Wp,
    const float* __restrict__ bp, float* __restrict__ out, int GB)
{
    int gb = blockIdx.x;
    int tid = threadIdx.x;
    float v = pooled[gb * 128 + tid] * Wp[tid];
    v += __shfl_down(v, 32);
    v += __shfl_down(v, 16);
    v += __shfl_down(v, 8);
    v += __shfl_down(v, 4);
    v += __shfl_down(v, 2);
    v += __shfl_down(v, 1);
    __shared__ float red[2];
    if ((tid & 63) == 0) red[tid >> 6] = v;
    __syncthreads();
    if (tid == 0) out[gb] = red[0] + red[1] + bp[0];
}

// ---------------- host ----------------
extern "C" void kernel_launch(void* const* d_in, const int* in_sizes, int n_in,
                              void* d_out, int out_size, void* d_ws, size_t ws_size,
                              hipStream_t stream) {
    const float* features = (const float*)d_in[0];
    const int* edge_index = (const int*)d_in[1];
    const int* lengths    = (const int*)d_in[2];
    const float* emb      = (const float*)d_in[3];
    const float* W_in     = (const float*)d_in[4];
    const float* b_in     = (const float*)d_in[5];
    const float* g_in     = (const float*)d_in[6];
    const float* beta_in  = (const float*)d_in[7];
    const float* msg_W    = (const float*)d_in[8];
    const float* msg_b    = (const float*)d_in[9];
    const float* msg_g    = (const float*)d_in[10];
    const float* msg_beta = (const float*)d_in[11];
    const float* W_proj   = (const float*)d_in[12];
    const float* b_proj   = (const float*)d_in[13];
    float* out = (float*)d_out;

    const int E = in_sizes[1] / 2;
    const int G = in_sizes[2];
    const int B = out_size / G;
    const int C = in_sizes[5];           // 128
    const int F = 128;
    const int N = in_sizes[0] / (B * F);
    const int M = B * N;
    const int L = in_sizes[9] / C;       // 3

    const int* rows = edge_index;
    const int* cols = edge_index + E;

    // workspace carve-up (16B-aligned)
    u16* buf0   = (u16*)d_ws;                               // M*128
    u16* buf1   = buf0 + (size_t)M * 128;                   // M*128
    u16* Wt_in  = buf1 + (size_t)M * 128;                   // 128*KP_IN
    u16* Wt_msg = Wt_in + 128 * KP_IN;                      // 3*128*KP_MP
    float* invdeg = (float*)(Wt_msg + 3 * 128 * KP_MP);     // N
    int*   deg    = (int*)(invdeg + N);                     // N (reused as cursor)
    float* pooled = (float*)(deg + N);                      // G*B*128
    int*   row_ptr = (int*)(pooled + (size_t)G * B * 128);  // N+1
    int*   col_sorted = row_ptr + N + 1;                    // E
    int*   bsum   = col_sorted + E;

    const int nb_scan = (N + SCAN_ELEMS - 1) / SCAN_ELEMS;
    const int ntiles = (M + 63) / 64;
    const int grid_g = ntiles < 1024 ? ntiles : 1024;

    // weight prep
    {
        int total = 128 * KP_IN + 3 * 128 * KP_MP;
        k_wprep<<<(total + 255) / 256, 256, 0, stream>>>(W_in, msg_W, Wt_in, Wt_msg);
    }

    // degree + CSR
    hipMemsetAsync(deg, 0, (size_t)N * sizeof(int), stream);
    k_deg<<<(E + 255) / 256, 256, 0, stream>>>(rows, deg, E);
    k_invdeg<<<(N + 255) / 256, 256, 0, stream>>>(deg, invdeg, N);
    k_scan1<<<nb_scan, SCAN_T, 0, stream>>>(deg, row_ptr, bsum, N);
    k_scan2<<<1, 1, 0, stream>>>(bsum, nb_scan, row_ptr, N);
    k_scan3<<<nb_scan, SCAN_T, 0, stream>>>(row_ptr, bsum, N);
    k_copy_cursor<<<(N + 255) / 256, 256, 0, stream>>>(row_ptr, deg, N);
    k_bucket<<<(E + 255) / 256, 256, 0, stream>>>(rows, cols, deg, col_sorted, E);

    // input layer -> buf0
    k_input_mfma<<<grid_g, 256, 0, stream>>>(features, emb, Wt_in,
                                             b_in, g_in, beta_in, buf0, M, ntiles);

    // fused mp layers (ping-pong)
    u16* bufs[2] = {buf0, buf1};
    int cur = 0;
    for (int l = 0; l < L; ++l) {
        k_mp_mfma<<<grid_g, 256, 0, stream>>>(row_ptr, col_sorted, invdeg,
                                              bufs[cur], Wt_msg + (size_t)l * 128 * KP_MP,
                                              msg_b + (size_t)l * C, msg_g + (size_t)l * C,
                                              msg_beta + (size_t)l * C,
                                              bufs[1 - cur], N, M, ntiles);
        cur = 1 - cur;
    }

    // pooling + projection
    const int SPLIT = 64;
    hipMemsetAsync(pooled, 0, (size_t)G * B * 128 * sizeof(float), stream);
    k_pool<<<G * B * SPLIT, 64, 0, stream>>>(bufs[cur], lengths, pooled, N, B, G, SPLIT);
    k_proj<<<G * B, 128, 0, stream>>>(pooled, W_proj, b_proj, out, G * B);
}

// Round 5
// 392.157 us; speedup vs baseline: 12.4916x; 1.0732x over previous
//
#include <hip/hip_runtime.h>
#include <cstddef>

#define LN_EPS 1e-5f
typedef unsigned short u16;
typedef unsigned int u32;
typedef __attribute__((ext_vector_type(8))) short bf16x8;
typedef __attribute__((ext_vector_type(4))) float f32x4;

constexpr int SCAN_T = 256, SCAN_V = 8, SCAN_ELEMS = SCAN_T * SCAN_V;
constexpr int KP = 136;   // K=128 padded to 136 elem (272B stride) for both layers

__device__ inline u16 f2bf(float f) {
    u32 u = __float_as_uint(f);
    u += 0x7FFFu + ((u >> 16) & 1u);
    return (u16)(u >> 16);
}
__device__ inline float bf2f(u16 h) { return __uint_as_float((u32)h << 16); }

__device__ inline void acc_u4(float* a, uint4 u) {
    a[0] += bf2f((u16)(u.x & 0xFFFF)); a[1] += bf2f((u16)(u.x >> 16));
    a[2] += bf2f((u16)(u.y & 0xFFFF)); a[3] += bf2f((u16)(u.y >> 16));
    a[4] += bf2f((u16)(u.z & 0xFFFF)); a[5] += bf2f((u16)(u.z >> 16));
    a[6] += bf2f((u16)(u.w & 0xFFFF)); a[7] += bf2f((u16)(u.w >> 16));
}

// ---------------- degree / inverse degree ----------------
__global__ __launch_bounds__(256) void k_deg(const int* __restrict__ rows,
                                             int* __restrict__ deg, int E) {
    int e = blockIdx.x * 256 + threadIdx.x;
    if (e < E) atomicAdd(&deg[rows[e]], 1);
}

__global__ __launch_bounds__(256) void k_invdeg(const int* __restrict__ deg,
                                                float* __restrict__ invdeg, int N) {
    int i = blockIdx.x * 256 + threadIdx.x;
    if (i < N) invdeg[i] = 1.0f / (float)max(deg[i], 1);
}

// ---------------- CSR build ----------------
__global__ __launch_bounds__(SCAN_T) void k_scan1(const int* __restrict__ deg,
                                                  int* __restrict__ row_ptr,
                                                  int* __restrict__ bsum, int N) {
    __shared__ int ts[SCAN_T];
    int t = threadIdx.x;
    int base = blockIdx.x * SCAN_ELEMS;
    int v[SCAN_V];
    int s = 0;
    #pragma unroll
    for (int j = 0; j < SCAN_V; ++j) {
        int i = base + t * SCAN_V + j;
        v[j] = (i < N) ? deg[i] : 0;
        s += v[j];
    }
    ts[t] = s;
    __syncthreads();
    for (int off = 1; off < SCAN_T; off <<= 1) {
        int val = (t >= off) ? ts[t - off] : 0;
        __syncthreads();
        ts[t] += val;
        __syncthreads();
    }
    int excl = (t > 0) ? ts[t - 1] : 0;
    #pragma unroll
    for (int j = 0; j < SCAN_V; ++j) {
        int i = base + t * SCAN_V + j;
        if (i < N) row_ptr[i] = excl;
        excl += v[j];
    }
    if (t == SCAN_T - 1) bsum[blockIdx.x] = ts[SCAN_T - 1];
}

__global__ void k_scan2(int* __restrict__ bsum, int nb, int* __restrict__ row_ptr, int N) {
    int run = 0;
    for (int i = 0; i < nb; ++i) {
        int v = bsum[i];
        bsum[i] = run;
        run += v;
    }
    row_ptr[N] = run;
}

__global__ __launch_bounds__(SCAN_T) void k_scan3(int* __restrict__ row_ptr,
                                                  const int* __restrict__ bsum, int N) {
    int add = bsum[blockIdx.x];
    int base = blockIdx.x * SCAN_ELEMS;
    #pragma unroll
    for (int j = 0; j < SCAN_V; ++j) {
        int i = base + threadIdx.x * SCAN_V + j;
        if (i < N) row_ptr[i] += add;
    }
}

__global__ __launch_bounds__(256) void k_copy_cursor(const int* __restrict__ row_ptr,
                                                     int* __restrict__ cursor, int N) {
    int i = blockIdx.x * 256 + threadIdx.x;
    if (i < N) cursor[i] = row_ptr[i];
}

__global__ __launch_bounds__(256) void k_bucket(const int* __restrict__ rows,
                                                const int* __restrict__ cols,
                                                int* __restrict__ cursor,
                                                int* __restrict__ col_sorted, int E) {
    int e = blockIdx.x * 256 + threadIdx.x;
    if (e < E) {
        int r = rows[e];
        int pos = atomicAdd(&cursor[r], 1);
        col_sorted[pos] = cols[e];
    }
}

// ---------------- weight prep ----------------
// Wt_in: [128 cols][KP] bf16, k=0 zero (feat0 weight dropped), k=1..127 = W_in[31+k][c]
// Wt_msg: [3][128 cols][KP] bf16
__global__ __launch_bounds__(256) void k_wprep(const float* __restrict__ W_in,
                                               const float* __restrict__ msg_W,
                                               u16* __restrict__ Wt_in,
                                               u16* __restrict__ Wt_msg) {
    int idx = blockIdx.x * 256 + threadIdx.x;
    const int t1 = 128 * KP;
    if (idx < t1) {
        int c = idx / KP, k = idx % KP;
        float v = (k >= 1 && k < 128) ? W_in[(31 + k) * 128 + c] : 0.f;
        Wt_in[idx] = f2bf(v);
    } else {
        idx -= t1;
        if (idx < 3 * 128 * KP) {
            int l = idx / (128 * KP);
            int r = idx % (128 * KP);
            int c = r / KP, k = r % KP;
            Wt_msg[idx] = (k < 128) ? f2bf(msg_W[l * 16384 + k * 128 + c]) : (u16)0;
        }
    }
}

// E_proj[op][c] = sum_j emb[op][j] * W_in[j][c]  (emb rows are concat slots 0..31)
__global__ __launch_bounds__(128) void k_eproj(const float* __restrict__ W_in,
                                               const float* __restrict__ emb,
                                               float* __restrict__ E_proj) {
    __shared__ float es[32];
    int op = blockIdx.x, c = threadIdx.x;
    if (c < 32) es[c] = emb[op * 32 + c];
    __syncthreads();
    float s = 0.f;
    #pragma unroll
    for (int j = 0; j < 32; ++j) s = fmaf(es[j], W_in[j * 128 + c], s);
    E_proj[op * 128 + c] = s;
}

// ---------------- input layer: MFMA bf16 (K=128, E_proj folded post-GEMM) -----
__global__ __launch_bounds__(256) void k_input_mfma(
    const float* __restrict__ features, const float* __restrict__ E_proj,
    const u16* __restrict__ Wt,
    const float* __restrict__ bias, const float* __restrict__ gain,
    const float* __restrict__ beta, u16* __restrict__ x, int M, int ntiles)
{
    __shared__ u16 A[64 * KP];
    __shared__ u16 Wl[128 * KP];
    __shared__ int ops[64];
    const int tid = threadIdx.x;
    const int lane = tid & 63, w = tid >> 6;
    const int r = tid >> 2, q = tid & 3;

    {   // stage W^T once per block
        const uint4* src = (const uint4*)Wt;
        uint4* dst = (uint4*)Wl;
        const int n16 = 128 * KP / 8;
        for (int i = tid; i < n16; i += 256) dst[i] = src[i];
    }
    // per-lane epilogue constants (8 cols each)
    float bsr[8], gsr[8], btr[8];
    #pragma unroll
    for (int t = 0; t < 8; ++t) {
        int col = t * 16 + (lane & 15);
        bsr[t] = bias[col]; gsr[t] = gain[col]; btr[t] = beta[col];
    }

    for (int tile = blockIdx.x; tile < ntiles; tile += gridDim.x) {
        const int node0 = tile * 64;
        __syncthreads();
        // stage features row r, 32 floats at q*32 -> A[r][q*32..]
        {
            int rg = min(node0 + r, M - 1);
            const float* fr = features + (size_t)rg * 128 + q * 32;
            u32 pk[16];
            float4 v0 = ((const float4*)fr)[0];
            if (q == 0) {
                int op = (int)v0.x;
                op = op < 0 ? 0 : (op > 127 ? 127 : op);
                ops[r] = op;
            }
            pk[0] = (u32)f2bf(v0.x) | ((u32)f2bf(v0.y) << 16);
            pk[1] = (u32)f2bf(v0.z) | ((u32)f2bf(v0.w) << 16);
            #pragma unroll
            for (int j = 1; j < 8; ++j) {
                float4 v = ((const float4*)fr)[j];
                pk[2 * j]     = (u32)f2bf(v.x) | ((u32)f2bf(v.y) << 16);
                pk[2 * j + 1] = (u32)f2bf(v.z) | ((u32)f2bf(v.w) << 16);
            }
            uint4* dst = (uint4*)&A[r * KP + q * 32];
            #pragma unroll
            for (int j = 0; j < 4; ++j)
                dst[j] = make_uint4(pk[4 * j], pk[4 * j + 1], pk[4 * j + 2], pk[4 * j + 3]);
        }
        __syncthreads();

        const int arow = w * 16 + (lane & 15);
        const int kq = (lane >> 4) * 8;
        bf16x8 a[4];
        #pragma unroll
        for (int kt = 0; kt < 4; ++kt)
            a[kt] = *(const bf16x8*)&A[arow * KP + kt * 32 + kq];
        f32x4 acc[8];
        #pragma unroll
        for (int t = 0; t < 8; ++t) {
            int bcol = t * 16 + (lane & 15);
            f32x4 c4 = {0.f, 0.f, 0.f, 0.f};
            #pragma unroll
            for (int kt = 0; kt < 4; ++kt) {
                bf16x8 b = *(const bf16x8*)&Wl[bcol * KP + kt * 32 + kq];
                c4 = __builtin_amdgcn_mfma_f32_16x16x32_bf16(a[kt], b, c4, 0, 0, 0);
            }
            acc[t] = c4;
        }
        // + E_proj + bias, silu, LN
        int opr[4];
        #pragma unroll
        for (int i = 0; i < 4; ++i) opr[i] = ops[w * 16 + (lane >> 4) * 4 + i];
        float s[4] = {0, 0, 0, 0}, sq[4] = {0, 0, 0, 0};
        #pragma unroll
        for (int t = 0; t < 8; ++t) {
            int col = t * 16 + (lane & 15);
            #pragma unroll
            for (int i = 0; i < 4; ++i) {
                float aY = acc[t][i] + bsr[t] + E_proj[opr[i] * 128 + col];
                float y = aY / (1.0f + __expf(-aY));
                acc[t][i] = y;
                s[i] += y;
                sq[i] = fmaf(y, y, sq[i]);
            }
        }
        #pragma unroll
        for (int m = 1; m <= 8; m <<= 1) {
            #pragma unroll
            for (int i = 0; i < 4; ++i) {
                s[i] += __shfl_xor(s[i], m);
                sq[i] += __shfl_xor(sq[i], m);
            }
        }
        #pragma unroll
        for (int i = 0; i < 4; ++i) {
            float mu = s[i] * (1.0f / 128.0f);
            float var = sq[i] * (1.0f / 128.0f) - mu * mu;
            float inv = rsqrtf(var + LN_EPS);
            int rg = node0 + w * 16 + (lane >> 4) * 4 + i;
            if (rg < M) {
                u16* xr = x + (size_t)rg * 128;
                #pragma unroll
                for (int t = 0; t < 8; ++t) {
                    int col = t * 16 + (lane & 15);
                    xr[col] = f2bf((acc[t][i] - mu) * inv * gsr[t] + btr[t]);
                }
            }
        }
    }
}

// ---------------- fused mp layer: CSR gather -> LDS -> MFMA ----------------
__global__ __launch_bounds__(256) void k_mp_mfma(
    const int* __restrict__ row_ptr, const int* __restrict__ col_sorted,
    const float* __restrict__ invdeg, const u16* __restrict__ xin,
    const u16* __restrict__ Wt, const float* __restrict__ bias,
    const float* __restrict__ gain, const float* __restrict__ beta,
    u16* __restrict__ xout, int N, int M, int ntiles)
{
    __shared__ u16 A[64 * KP];
    __shared__ u16 Wl[128 * KP];
    const int tid = threadIdx.x;
    const int lane = tid & 63, w = tid >> 6;
    const int r = tid >> 2, q = tid & 3;

    {   // stage W^T once per block
        const uint4* src = (const uint4*)Wt;
        uint4* dst = (uint4*)Wl;
        const int n16 = 128 * KP / 8;
        for (int i = tid; i < n16; i += 256) dst[i] = src[i];
    }
    float bsr[8], gsr[8], btr[8];
    #pragma unroll
    for (int t = 0; t < 8; ++t) {
        int col = t * 16 + (lane & 15);
        bsr[t] = bias[col]; gsr[t] = gain[col]; btr[t] = beta[col];
    }

    for (int tile = blockIdx.x; tile < ntiles; tile += gridDim.x) {
        const int node0 = tile * 64;
        __syncthreads();
        // gather: 4 threads/row, 32 cols each, f32 accumulate, 2-edge unroll
        {
            int rg = min(node0 + r, M - 1);
            int b = rg / N;
            int nrow = rg - b * N;
            int e0 = row_ptr[nrow], e1 = row_ptr[nrow + 1];
            float sc = invdeg[nrow];
            const u32* xb = (const u32*)xin + (size_t)b * N * 64 + q * 16;
            float fa[32];
            #pragma unroll
            for (int j = 0; j < 32; ++j) fa[j] = 0.f;
            int e = e0;
            for (; e + 2 <= e1; e += 2) {
                int c0 = col_sorted[e], c1 = col_sorted[e + 1];
                const uint4* p0 = (const uint4*)(xb + (size_t)c0 * 64);
                const uint4* p1 = (const uint4*)(xb + (size_t)c1 * 64);
                uint4 u0 = p0[0], u1 = p0[1], u2 = p0[2], u3 = p0[3];
                uint4 w0 = p1[0], w1 = p1[1], w2 = p1[2], w3 = p1[3];
                acc_u4(fa + 0, u0);  acc_u4(fa + 8, u1);
                acc_u4(fa + 16, u2); acc_u4(fa + 24, u3);
                acc_u4(fa + 0, w0);  acc_u4(fa + 8, w1);
                acc_u4(fa + 16, w2); acc_u4(fa + 24, w3);
            }
            if (e < e1) {
                const uint4* p0 = (const uint4*)(xb + (size_t)col_sorted[e] * 64);
                uint4 u0 = p0[0], u1 = p0[1], u2 = p0[2], u3 = p0[3];
                acc_u4(fa + 0, u0);  acc_u4(fa + 8, u1);
                acc_u4(fa + 16, u2); acc_u4(fa + 24, u3);
            }
            u32 pk[16];
            #pragma unroll
            for (int j = 0; j < 16; ++j)
                pk[j] = (u32)f2bf(fa[2 * j] * sc) | ((u32)f2bf(fa[2 * j + 1] * sc) << 16);
            uint4* dst = (uint4*)&A[r * KP + q * 32];
            #pragma unroll
            for (int j = 0; j < 4; ++j)
                dst[j] = make_uint4(pk[4 * j], pk[4 * j + 1], pk[4 * j + 2], pk[4 * j + 3]);
        }
        __syncthreads();

        const int arow = w * 16 + (lane & 15);
        const int kq = (lane >> 4) * 8;
        bf16x8 a[4];
        #pragma unroll
        for (int kt = 0; kt < 4; ++kt)
            a[kt] = *(const bf16x8*)&A[arow * KP + kt * 32 + kq];
        f32x4 acc[8];
        #pragma unroll
        for (int t = 0; t < 8; ++t) {
            int bcol = t * 16 + (lane & 15);
            f32x4 c4 = {0.f, 0.f, 0.f, 0.f};
            #pragma unroll
            for (int kt = 0; kt < 4; ++kt) {
                bf16x8 b = *(const bf16x8*)&Wl[bcol * KP + kt * 32 + kq];
                c4 = __builtin_amdgcn_mfma_f32_16x16x32_bf16(a[kt], b, c4, 0, 0, 0);
            }
            acc[t] = c4;
        }
        float s[4] = {0, 0, 0, 0}, sq[4] = {0, 0, 0, 0};
        #pragma unroll
        for (int t = 0; t < 8; ++t) {
            #pragma unroll
            for (int i = 0; i < 4; ++i) {
                float aY = acc[t][i] + bsr[t];
                float y = aY / (1.0f + __expf(-aY));
                acc[t][i] = y;
                s[i] += y;
                sq[i] = fmaf(y, y, sq[i]);
            }
        }
        #pragma unroll
        for (int m = 1; m <= 8; m <<= 1) {
            #pragma unroll
            for (int i = 0; i < 4; ++i) {
                s[i] += __shfl_xor(s[i], m);
                sq[i] += __shfl_xor(sq[i], m);
            }
        }
        #pragma unroll
        for (int i = 0; i < 4; ++i) {
            float mu = s[i] * (1.0f / 128.0f);
            float var = sq[i] * (1.0f / 128.0f) - mu * mu;
            float inv = rsqrtf(var + LN_EPS);
            int rg = node0 + w * 16 + (lane >> 4) * 4 + i;
            if (rg < M) {
                u16* xr = xout + (size_t)rg * 128;
                #pragma unroll
                for (int t = 0; t < 8; ++t) {
                    int col = t * 16 + (lane & 15);
                    xr[col] = f2bf((acc[t][i] - mu) * inv * gsr[t] + btr[t]);
                }
            }
        }
    }
}

// ---------------- pooling (8-unrolled) ----------------
__global__ __launch_bounds__(64) void k_pool(
    const u16* __restrict__ x, const int* __restrict__ lengths,
    float* __restrict__ pooled, int N, int B, int G, int SPLIT)
{
    int blk = blockIdx.x;
    int split = blk % SPLIT;
    int gb = blk / SPLIT;
    int b = gb % B, g = gb / B;
    int lane = threadIdx.x;
    int start = 0;
    for (int i = 0; i < g; ++i) start += lengths[i];
    int len = lengths[g];
    int chunk = (len + SPLIT - 1) / SPLIT;
    int n0 = start + split * chunk;
    int n1 = min(start + len, n0 + chunk);
    const u32* xb = (const u32*)x + (size_t)b * N * 64;
    float sx = 0.f, sy = 0.f;
    int n = n0;
    for (; n + 8 <= n1; n += 8) {
        u32 v0 = xb[(size_t)(n + 0) * 64 + lane];
        u32 v1 = xb[(size_t)(n + 1) * 64 + lane];
        u32 v2 = xb[(size_t)(n + 2) * 64 + lane];
        u32 v3 = xb[(size_t)(n + 3) * 64 + lane];
        u32 v4 = xb[(size_t)(n + 4) * 64 + lane];
        u32 v5 = xb[(size_t)(n + 5) * 64 + lane];
        u32 v6 = xb[(size_t)(n + 6) * 64 + lane];
        u32 v7 = xb[(size_t)(n + 7) * 64 + lane];
        sx += bf2f((u16)(v0 & 0xFFFF)) + bf2f((u16)(v1 & 0xFFFF)) +
              bf2f((u16)(v2 & 0xFFFF)) + bf2f((u16)(v3 & 0xFFFF)) +
              bf2f((u16)(v4 & 0xFFFF)) + bf2f((u16)(v5 & 0xFFFF)) +
              bf2f((u16)(v6 & 0xFFFF)) + bf2f((u16)(v7 & 0xFFFF));
        sy += bf2f((u16)(v0 >> 16)) + bf2f((u16)(v1 >> 16)) +
              bf2f((u16)(v2 >> 16)) + bf2f((u16)(v3 >> 16)) +
              bf2f((u16)(v4 >> 16)) + bf2f((u16)(v5 >> 16)) +
              bf2f((u16)(v6 >> 16)) + bf2f((u16)(v7 >> 16));
    }
    for (; n < n1; ++n) {
        u32 v = xb[(size_t)n * 64 + lane];
        sx += bf2f((u16)(v & 0xFFFF));
        sy += bf2f((u16)(v >> 16));
    }
    if (n1 > n0) {
        atomicAdd(&pooled[(g * B + b) * 128 + lane * 2 + 0], sx);
        atomicAdd(&pooled[(g * B + b) * 128 + lane * 2 + 1], sy);
    }
}

__global__ __launch_bounds__(128) void k_proj(
    const float* __restrict__ pooled, const float* __restrict__ Wp,
    const float* __restrict__ bp, float* __restrict__ out, int GB)
{
    int gb = blockIdx.x;
    int tid = threadIdx.x;
    float v = pooled[gb * 128 + tid] * Wp[tid];
    v += __shfl_down(v, 32);
    v += __shfl_down(v, 16);
    v += __shfl_down(v, 8);
    v += __shfl_down(v, 4);
    v += __shfl_down(v, 2);
    v += __shfl_down(v, 1);
    __shared__ float red[2];
    if ((tid & 63) == 0) red[tid >> 6] = v;
    __syncthreads();
    if (tid == 0) out[gb] = red[0] + red[1] + bp[0];
}

// ---------------- host ----------------
extern "C" void kernel_launch(void* const* d_in, const int* in_sizes, int n_in,
                              void* d_out, int out_size, void* d_ws, size_t ws_size,
                              hipStream_t stream) {
    const float* features = (const float*)d_in[0];
    const int* edge_index = (const int*)d_in[1];
    const int* lengths    = (const int*)d_in[2];
    const float* emb      = (const float*)d_in[3];
    const float* W_in     = (const float*)d_in[4];
    const float* b_in     = (const float*)d_in[5];
    const float* g_in     = (const float*)d_in[6];
    const float* beta_in  = (const float*)d_in[7];
    const float* msg_W    = (const float*)d_in[8];
    const float* msg_b    = (const float*)d_in[9];
    const float* msg_g    = (const float*)d_in[10];
    const float* msg_beta = (const float*)d_in[11];
    const float* W_proj   = (const float*)d_in[12];
    const float* b_proj   = (const float*)d_in[13];
    float* out = (float*)d_out;

    const int E = in_sizes[1] / 2;
    const int G = in_sizes[2];
    const int B = out_size / G;
    const int C = in_sizes[5];           // 128
    const int F = 128;
    const int N = in_sizes[0] / (B * F);
    const int M = B * N;
    const int L = in_sizes[9] / C;       // 3

    const int* rows = edge_index;
    const int* cols = edge_index + E;

    // workspace carve-up (16B-aligned)
    u16* buf0   = (u16*)d_ws;                               // M*128
    u16* buf1   = buf0 + (size_t)M * 128;                   // M*128
    u16* Wt_in  = buf1 + (size_t)M * 128;                   // 128*KP
    u16* Wt_msg = Wt_in + 128 * KP;                         // 3*128*KP
    float* E_proj = (float*)(Wt_msg + 3 * 128 * KP);        // 128*128 f32
    float* invdeg = E_proj + 128 * 128;                     // N
    int*   deg    = (int*)(invdeg + N);                     // N (reused as cursor)
    float* pooled = (float*)(deg + N);                      // G*B*128
    int*   row_ptr = (int*)(pooled + (size_t)G * B * 128);  // N+1
    int*   col_sorted = row_ptr + N + 1;                    // E
    int*   bsum   = col_sorted + E;

    const int nb_scan = (N + SCAN_ELEMS - 1) / SCAN_ELEMS;
    const int ntiles = (M + 63) / 64;
    const int grid_g = ntiles < 768 ? ntiles : 768;

    // weight prep
    {
        int total = 4 * 128 * KP;
        k_wprep<<<(total + 255) / 256, 256, 0, stream>>>(W_in, msg_W, Wt_in, Wt_msg);
        k_eproj<<<128, 128, 0, stream>>>(W_in, emb, E_proj);
    }

    // degree + CSR
    hipMemsetAsync(deg, 0, (size_t)N * sizeof(int), stream);
    k_deg<<<(E + 255) / 256, 256, 0, stream>>>(rows, deg, E);
    k_invdeg<<<(N + 255) / 256, 256, 0, stream>>>(deg, invdeg, N);
    k_scan1<<<nb_scan, SCAN_T, 0, stream>>>(deg, row_ptr, bsum, N);
    k_scan2<<<1, 1, 0, stream>>>(bsum, nb_scan, row_ptr, N);
    k_scan3<<<nb_scan, SCAN_T, 0, stream>>>(row_ptr, bsum, N);
    k_copy_cursor<<<(N + 255) / 256, 256, 0, stream>>>(row_ptr, deg, N);
    k_bucket<<<(E + 255) / 256, 256, 0, stream>>>(rows, cols, deg, col_sorted, E);

    // input layer -> buf0
    k_input_mfma<<<grid_g, 256, 0, stream>>>(features, E_proj, Wt_in,
                                             b_in, g_in, beta_in, buf0, M, ntiles);

    // fused mp layers (ping-pong)
    u16* bufs[2] = {buf0, buf1};
    int cur = 0;
    for (int l = 0; l < L; ++l) {
        k_mp_mfma<<<grid_g, 256, 0, stream>>>(row_ptr, col_sorted, invdeg,
                                              bufs[cur], Wt_msg + (size_t)l * 128 * KP,
                                              msg_b + (size_t)l * C, msg_g + (size_t)l * C,
                                              msg_beta + (size_t)l * C,
                                              bufs[1 - cur], N, M, ntiles);
        cur = 1 - cur;
    }

    // pooling + projection
    const int SPLIT = 128;
    hipMemsetAsync(pooled, 0, (size_t)G * B * 128 * sizeof(float), stream);
    k_pool<<<G * B * SPLIT, 64, 0, stream>>>(bufs[cur], lengths, pooled, N, B, G, SPLIT);
    k_proj<<<G * B, 128, 0, stream>>>(pooled, W_proj, b_proj, out, G * B);
}